// Round 4
// baseline (170.485 us; speedup 1.0000x reference)
//
#include <hip/hip_runtime.h>

#define H_IMG 128
#define W_IMG 128
#define NQ (H_IMG * W_IMG)
#define CIN 256
#define NH 8
#define NP 4
#define DH 32
#define LDSP 264  // padded LDS row stride (bf16 elems); 264%32=8 -> 2-way max aliasing (free)
#define QB 32     // queries per K2 block (was 64): halves LDS, doubles grid -> 4 blocks/CU

typedef __bf16 bf16x4 __attribute__((ext_vector_type(4)));
typedef __bf16 bf16x8 __attribute__((ext_vector_type(8)));
typedef float f32x4 __attribute__((ext_vector_type(4)));

// ---------------- weight prep: transpose to BT[N][K] and cast to bf16 ----------------
__global__ __launch_bounds__(256) void prep_weights(
    const float* __restrict__ Wval, const float* __restrict__ Wout,
    const float* __restrict__ Woff, const float* __restrict__ Wattn,
    const float* __restrict__ boff, const float* __restrict__ battn,
    __bf16* __restrict__ btv, __bf16* __restrict__ bto,
    __bf16* __restrict__ btoa, float* __restrict__ bias96) {
  int id = blockIdx.x * 256 + threadIdx.x;
  if (id < 256 * 256) {
    int n = id >> 8, k = id & 255;
    btv[n * 256 + k] = (__bf16)Wval[k * 256 + n];
    bto[n * 256 + k] = (__bf16)Wout[k * 256 + n];
  }
  if (id < 96 * 256) {
    int n = id >> 8, k = id & 255;
    float w = (n < 64) ? Woff[k * 64 + n] : Wattn[k * 32 + (n - 64)];
    btoa[n * 256 + k] = (__bf16)w;
  }
  if (id < 96) {
    bias96[id] = (id < 64) ? boff[id] : battn[id - 64];
  }
}

// ---------------- K1: v = value @ W_val + b_val (head-planar bf16 out) -------------
__global__ __launch_bounds__(256) void gemm_v(
    const float* __restrict__ A, const __bf16* __restrict__ BT,
    const float* __restrict__ bias, __bf16* __restrict__ v, int M) {
  const int t = threadIdx.x;
  const int lane = t & 63;
  const int wave = t >> 6;
  const int r = lane & 15;
  const int q = lane >> 4;
  const int gm0 = blockIdx.x * 64;
  const int wn = wave * 64;

  __shared__ __bf16 As[64 * LDSP];

#pragma unroll
  for (int i = 0; i < 16; ++i) {
    int g = i * 256 + t;
    int row = g >> 6, c4 = g & 63;
    float4 f = *(const float4*)(A + (size_t)(gm0 + row) * 256 + c4 * 4);
    bf16x4 hh;
    hh[0] = (__bf16)f.x; hh[1] = (__bf16)f.y;
    hh[2] = (__bf16)f.z; hh[3] = (__bf16)f.w;
    *(bf16x4*)(&As[row * LDSP + c4 * 4]) = hh;
  }
  __syncthreads();

  f32x4 acc[4][4];
#pragma unroll
  for (int mt = 0; mt < 4; ++mt)
#pragma unroll
    for (int nt = 0; nt < 4; ++nt) acc[mt][nt] = (f32x4){0.f, 0.f, 0.f, 0.f};

#pragma unroll
  for (int kt = 0; kt < 8; ++kt) {
    const int ko = kt * 32 + q * 8;
    bf16x8 a[4], b[4];
#pragma unroll
    for (int mt = 0; mt < 4; ++mt)
      a[mt] = *(const bf16x8*)(&As[(mt * 16 + r) * LDSP + ko]);
#pragma unroll
    for (int nt = 0; nt < 4; ++nt)
      b[nt] = *(const bf16x8*)(BT + (size_t)(wn + nt * 16 + r) * 256 + ko);
#pragma unroll
    for (int mt = 0; mt < 4; ++mt)
#pragma unroll
      for (int nt = 0; nt < 4; ++nt)
        acc[mt][nt] =
            __builtin_amdgcn_mfma_f32_16x16x32_bf16(a[mt], b[nt], acc[mt][nt], 0, 0, 0);
  }

#pragma unroll
  for (int mt = 0; mt < 4; ++mt)
#pragma unroll
    for (int nt = 0; nt < 4; ++nt)
#pragma unroll
      for (int rr = 0; rr < 4; ++rr) {
        int row = gm0 + mt * 16 + q * 4 + rr;
        int col = wn + nt * 16 + r;
        v[((size_t)(col >> 5) * M + row) * 32 + (col & 31)] =
            (__bf16)(acc[mt][nt][rr] + bias[col]);
      }
}

// ---------------- K2: oa GEMM + sampling + output GEMM, fully fused ----------------
// 32 queries/block, 256 threads, 1024 blocks. LDS = 32*264*2 + 32*100*4 = 29,696 B
// -> grid gives 4 blocks/CU (LDS would allow 5) = 16 waves/CU, 2x round-3's 8.
// Phase 3 keeps the proven 4-lane-per-(q,h) c8 mapping (lanes 4i..4i+3 read
// contiguous 64B per corner); each thread now covers 4 heads (hgrp split) not 8.
// 4 co-resident blocks sit in DIFFERENT phases -> sampling overlaps MFMA.
// __launch_bounds__(256,2): no VGPR cap tighter than 256 -> no spill (round-1 lesson).
__global__ __launch_bounds__(256, 2) void oa_sample_out(
    const float* __restrict__ query, const __bf16* __restrict__ btoa,
    const float* __restrict__ bias96, const __bf16* __restrict__ v,
    const __bf16* __restrict__ bto, const float* __restrict__ b_out,
    float* __restrict__ out, int M) {
  const int t = threadIdx.x;
  const int lane = t & 63;
  const int wave = t >> 6;
  const int r = lane & 15;
  const int q = lane >> 4;
  const int gm0 = blockIdx.x * QB;

  __shared__ __bf16 As[QB * LDSP];
  __shared__ float oas[QB * 100];

  // ---- phase 1: stage query (32 x 256 fp32 -> bf16) ----
#pragma unroll
  for (int i = 0; i < 8; ++i) {
    int g = i * 256 + t;
    int row = g >> 6, c4 = g & 63;
    float4 f = *(const float4*)(query + (size_t)(gm0 + row) * 256 + c4 * 4);
    bf16x4 hh;
    hh[0] = (__bf16)f.x; hh[1] = (__bf16)f.y;
    hh[2] = (__bf16)f.z; hh[3] = (__bf16)f.w;
    *(bf16x4*)(&As[row * LDSP + c4 * 4]) = hh;
  }
  __syncthreads();

  // ---- phase 2: oa GEMM 32x96 (wave: 1 m-tile x 3 n-tiles) ----
  {
    const int wm = (wave & 1) * 16;
    const int n0 = (wave >> 1) * 48;
    f32x4 acc[3];
#pragma unroll
    for (int nt = 0; nt < 3; ++nt) acc[nt] = (f32x4){0.f, 0.f, 0.f, 0.f};
#pragma unroll
    for (int kt = 0; kt < 8; ++kt) {
      const int ko = kt * 32 + q * 8;
      bf16x8 a = *(const bf16x8*)(&As[(wm + r) * LDSP + ko]);
      bf16x8 b[3];
#pragma unroll
      for (int nt = 0; nt < 3; ++nt)
        b[nt] = *(const bf16x8*)(btoa + (size_t)(n0 + nt * 16 + r) * 256 + ko);
#pragma unroll
      for (int nt = 0; nt < 3; ++nt)
        acc[nt] = __builtin_amdgcn_mfma_f32_16x16x32_bf16(a, b[nt], acc[nt], 0, 0, 0);
    }
#pragma unroll
    for (int nt = 0; nt < 3; ++nt)
#pragma unroll
      for (int rr = 0; rr < 4; ++rr) {
        int rl = wm + q * 4 + rr;
        int col = n0 + nt * 16 + r;
        oas[rl * 100 + col] = acc[nt][rr] + bias96[col];
      }
  }
  __syncthreads();  // oas ready; all As reads drained -> As reusable

  // ---- phase 3: sample; thread slot = (query, head-group of 4) x c8 split ----
  {
    const int slot = t >> 2;          // 64 slots
    const int qrow = slot & (QB - 1); // 32 queries
    const int hgrp = slot >> 5;       // 2 head groups of 4
    const int c8 = (t & 3) * 8;
    const int row = gm0 + qrow;
    const int b = row >> 14;  // nq = 16384
    const int qi = row & (NQ - 1);
    const int x = qi & (W_IMG - 1);
    const int y = qi >> 7;
    const float* oar = &oas[qrow * 100];
#pragma unroll
    for (int hh_ = 0; hh_ < 4; ++hh_) {
      const int h = hgrp * 4 + hh_;
      float l0 = oar[64 + h * 4 + 0];
      float l1 = oar[64 + h * 4 + 1];
      float l2 = oar[64 + h * 4 + 2];
      float l3 = oar[64 + h * 4 + 3];
      float mx = fmaxf(fmaxf(l0, l1), fmaxf(l2, l3));
      float e0 = __expf(l0 - mx), e1 = __expf(l1 - mx);
      float e2 = __expf(l2 - mx), e3 = __expf(l3 - mx);
      float inv = 1.f / (e0 + e1 + e2 + e3);
      float awp[4] = {e0 * inv, e1 * inv, e2 * inv, e3 * inv};

      // -- stage 1: all 16 byte-offsets + weights --
      int offs[16];
      float wvs[16];
#pragma unroll
      for (int p = 0; p < NP; ++p) {
        float ox = oar[h * 8 + p * 2 + 0];
        float oy = oar[h * 8 + p * 2 + 1];
        float ix = (float)x + ox;
        float iy = (float)y + oy;
        float x0f = floorf(ix), y0f = floorf(iy);
        float wx1 = ix - x0f, wy1 = iy - y0f;
        int x0 = (int)x0f, y0 = (int)y0f;
        float wgt[4] = {(1.f - wx1) * (1.f - wy1), wx1 * (1.f - wy1),
                        (1.f - wx1) * wy1, wx1 * wy1};
        int xs[4] = {x0, x0 + 1, x0, x0 + 1};
        int ysv[4] = {y0, y0, y0 + 1, y0 + 1};
#pragma unroll
        for (int c = 0; c < 4; ++c) {
          int xi = xs[c], yi = ysv[c];
          bool valid = (xi >= 0) & (xi < W_IMG) & (yi >= 0) & (yi < H_IMG);
          int xc = xi < 0 ? 0 : (xi > W_IMG - 1 ? W_IMG - 1 : xi);
          int yc = yi < 0 ? 0 : (yi > H_IMG - 1 ? H_IMG - 1 : yi);
          offs[p * 4 + c] = (yc * W_IMG + xc) * (DH * 2);  // byte offset into head plane
          wvs[p * 4 + c] = awp[p] * wgt[c] * (valid ? 1.f : 0.f);
        }
      }

      // -- stage 2: issue all 16 loads as a batch --
      const char* vb =
          (const char*)v + ((size_t)h * M + (size_t)b * NQ) * (DH * 2) + c8 * 2;
      bf16x8 g[16];
#pragma unroll
      for (int i = 0; i < 16; ++i) g[i] = *(const bf16x8*)(vb + offs[i]);

      // -- stage 3: accumulate --
      float fa[8] = {0.f, 0.f, 0.f, 0.f, 0.f, 0.f, 0.f, 0.f};
#pragma unroll
      for (int i = 0; i < 16; ++i) {
        float wv = wvs[i];
#pragma unroll
        for (int j = 0; j < 8; ++j) fa[j] += wv * (float)g[i][j];
      }

      bf16x8 o;
#pragma unroll
      for (int j = 0; j < 8; ++j) o[j] = (__bf16)fa[j];
      *(bf16x8*)(&As[qrow * LDSP + h * DH + c8]) = o;
    }
  }
  __syncthreads();  // attn tile ready in As

  // ---- phase 4: out GEMM 32x256 (wave: 2 m-tiles x 4 n-tiles) ----
  {
    const int wn = wave * 64;
    f32x4 acc[2][4];
#pragma unroll
    for (int mt = 0; mt < 2; ++mt)
#pragma unroll
      for (int nt = 0; nt < 4; ++nt) acc[mt][nt] = (f32x4){0.f, 0.f, 0.f, 0.f};
#pragma unroll
    for (int kt = 0; kt < 8; ++kt) {
      const int ko = kt * 32 + q * 8;
      bf16x8 a[2], b[4];
#pragma unroll
      for (int mt = 0; mt < 2; ++mt)
        a[mt] = *(const bf16x8*)(&As[(mt * 16 + r) * LDSP + ko]);
#pragma unroll
      for (int nt = 0; nt < 4; ++nt)
        b[nt] = *(const bf16x8*)(bto + (size_t)(wn + nt * 16 + r) * 256 + ko);
#pragma unroll
      for (int mt = 0; mt < 2; ++mt)
#pragma unroll
        for (int nt = 0; nt < 4; ++nt)
          acc[mt][nt] =
              __builtin_amdgcn_mfma_f32_16x16x32_bf16(a[mt], b[nt], acc[mt][nt], 0, 0, 0);
    }
#pragma unroll
    for (int mt = 0; mt < 2; ++mt)
#pragma unroll
      for (int nt = 0; nt < 4; ++nt)
#pragma unroll
        for (int rr = 0; rr < 4; ++rr) {
          int row = gm0 + mt * 16 + q * 4 + rr;
          int col = wn + nt * 16 + r;
          out[(size_t)row * 256 + col] =
              acc[mt][nt][rr] + b_out[col] + query[(size_t)row * 256 + col];
        }
  }
}

extern "C" void kernel_launch(void* const* d_in, const int* in_sizes, int n_in,
                              void* d_out, int out_size, void* d_ws, size_t ws_size,
                              hipStream_t stream) {
  const float* query  = (const float*)d_in[0];
  const float* value  = (const float*)d_in[1];
  const float* W_off  = (const float*)d_in[2];
  const float* b_off  = (const float*)d_in[3];
  const float* W_attn = (const float*)d_in[4];
  const float* b_attn = (const float*)d_in[5];
  const float* W_val  = (const float*)d_in[6];
  const float* b_val  = (const float*)d_in[7];
  const float* W_out  = (const float*)d_in[8];
  const float* b_out  = (const float*)d_in[9];
  float* out = (float*)d_out;

  char* ws = (char*)d_ws;
  __bf16* btv    = (__bf16*)(ws + 0);          // 128 KB
  __bf16* bto    = (__bf16*)(ws + 131072);     // 128 KB
  __bf16* btoa   = (__bf16*)(ws + 262144);     // 48 KB
  float*  bias96 = (float*)(ws + 311296);      // 384 B
  __bf16* v      = (__bf16*)(ws + 524288);     // 16 MB (bf16, head-planar)

  const int M = in_sizes[0] / CIN;  // 32768 = bs * nq

  prep_weights<<<256, 256, 0, stream>>>(W_val, W_out, W_off, W_attn,
                                        b_off, b_attn, btv, bto, btoa, bias96);
  gemm_v<<<M / 64, 256, 0, stream>>>(value, btv, b_val, v, M);
  oa_sample_out<<<M / QB, 256, 0, stream>>>(query, btoa, bias96, v, bto, b_out, out, M);
}

// Round 5
// 166.557 us; speedup vs baseline: 1.0236x; 1.0236x over previous
//
#include <hip/hip_runtime.h>

#define H_IMG 128
#define W_IMG 128
#define NQ (H_IMG * W_IMG)
#define CIN 256
#define NH 8
#define NP 4
#define DH 32
#define LDSP 264  // padded LDS row stride (bf16 elems); 264%32=8 -> 2-way max aliasing (free)
#define VQB 32    // rows per gemm_v block: grid 1024 -> 4 blocks/CU (was 512 -> 2/CU)

typedef __bf16 bf16x4 __attribute__((ext_vector_type(4)));
typedef __bf16 bf16x8 __attribute__((ext_vector_type(8)));
typedef float f32x4 __attribute__((ext_vector_type(4)));

// ---------------- weight prep: transpose to BT[N][K] and cast to bf16 ----------------
__global__ __launch_bounds__(256) void prep_weights(
    const float* __restrict__ Wval, const float* __restrict__ Wout,
    const float* __restrict__ Woff, const float* __restrict__ Wattn,
    const float* __restrict__ boff, const float* __restrict__ battn,
    __bf16* __restrict__ btv, __bf16* __restrict__ bto,
    __bf16* __restrict__ btoa, float* __restrict__ bias96) {
  int id = blockIdx.x * 256 + threadIdx.x;
  if (id < 256 * 256) {
    int n = id >> 8, k = id & 255;
    btv[n * 256 + k] = (__bf16)Wval[k * 256 + n];
    bto[n * 256 + k] = (__bf16)Wout[k * 256 + n];
  }
  if (id < 96 * 256) {
    int n = id >> 8, k = id & 255;
    float w = (n < 64) ? Woff[k * 64 + n] : Wattn[k * 32 + (n - 64)];
    btoa[n * 256 + k] = (__bf16)w;
  }
  if (id < 96) {
    bias96[id] = (id < 64) ? boff[id] : battn[id - 64];
  }
}

// ---------------- K1: v = value @ W_val + b_val (head-planar bf16 out) -------------
// REWORKED this round: 32-row tiles, grid = M/32 = 1024 blocks -> 4 blocks/CU
// (was 64-row tiles, 512 blocks = exactly 2/CU). This is a streaming GEMM
// (read 33.5 MB A + write 16 MB v, B is 128 KB L2-hot): doubling resident waves
// doubles in-flight staging loads -> moves toward the HBM roofline (~8 us floor).
// LDS 16.9 KB, acc 32 VGPR/thread -> no occupancy cap from VGPR/LDS; grid binds at 4.
// Wave w covers all 32 rows (2 m-tiles) x cols [w*64, w*64+64) (4 n-tiles).
__global__ __launch_bounds__(256, 2) void gemm_v(
    const float* __restrict__ A, const __bf16* __restrict__ BT,
    const float* __restrict__ bias, __bf16* __restrict__ v, int M) {
  const int t = threadIdx.x;
  const int lane = t & 63;
  const int wave = t >> 6;
  const int r = lane & 15;
  const int q = lane >> 4;
  const int gm0 = blockIdx.x * VQB;
  const int wn = wave * 64;

  __shared__ __bf16 As[VQB * LDSP];

  // stage A (32 x 256 fp32 -> bf16), coalesced, conflict-free
#pragma unroll
  for (int i = 0; i < 8; ++i) {
    int g = i * 256 + t;
    int row = g >> 6, c4 = g & 63;
    float4 f = *(const float4*)(A + (size_t)(gm0 + row) * 256 + c4 * 4);
    bf16x4 hh;
    hh[0] = (__bf16)f.x; hh[1] = (__bf16)f.y;
    hh[2] = (__bf16)f.z; hh[3] = (__bf16)f.w;
    *(bf16x4*)(&As[row * LDSP + c4 * 4]) = hh;
  }
  __syncthreads();

  f32x4 acc[2][4];
#pragma unroll
  for (int mt = 0; mt < 2; ++mt)
#pragma unroll
    for (int nt = 0; nt < 4; ++nt) acc[mt][nt] = (f32x4){0.f, 0.f, 0.f, 0.f};

#pragma unroll
  for (int kt = 0; kt < 8; ++kt) {
    const int ko = kt * 32 + q * 8;
    bf16x8 a[2], b[4];
#pragma unroll
    for (int mt = 0; mt < 2; ++mt)
      a[mt] = *(const bf16x8*)(&As[(mt * 16 + r) * LDSP + ko]);
#pragma unroll
    for (int nt = 0; nt < 4; ++nt)
      b[nt] = *(const bf16x8*)(BT + (size_t)(wn + nt * 16 + r) * 256 + ko);
#pragma unroll
    for (int mt = 0; mt < 2; ++mt)
#pragma unroll
      for (int nt = 0; nt < 4; ++nt)
        acc[mt][nt] =
            __builtin_amdgcn_mfma_f32_16x16x32_bf16(a[mt], b[nt], acc[mt][nt], 0, 0, 0);
  }

  // epilogue: head-planar scatter v[head][row][col&31]
#pragma unroll
  for (int mt = 0; mt < 2; ++mt)
#pragma unroll
    for (int nt = 0; nt < 4; ++nt)
#pragma unroll
      for (int rr = 0; rr < 4; ++rr) {
        int row = gm0 + mt * 16 + q * 4 + rr;
        int col = wn + nt * 16 + r;
        v[((size_t)(col >> 5) * M + row) * 32 + (col & 31)] =
            (__bf16)(acc[mt][nt][rr] + bias[col]);
      }
}

// ---------------- K2: oa GEMM + sampling + output GEMM, fully fused ----------------
// RESTORED to the round-3 config (best measured: ~46 us). 64 queries, 256 threads.
// Round-4 falsified the occupancy theory for this kernel: 2x waves (QB=32, occ 34%)
// gave the SAME time -> phase 3 saturates a per-CU shared resource (scattered-line
// throughput through TA/L1), invariant to wave count. Do not re-try occupancy here.
// Phase 3 keeps the 4-lane-per-(q,h) c8 mapping (contiguous 64B per corner).
__global__ __launch_bounds__(256, 2) void oa_sample_out(
    const float* __restrict__ query, const __bf16* __restrict__ btoa,
    const float* __restrict__ bias96, const __bf16* __restrict__ v,
    const __bf16* __restrict__ bto, const float* __restrict__ b_out,
    float* __restrict__ out, int M) {
  const int t = threadIdx.x;
  const int lane = t & 63;
  const int wave = t >> 6;
  const int r = lane & 15;
  const int q = lane >> 4;
  const int gm0 = blockIdx.x * 64;

  __shared__ __bf16 As[64 * LDSP];
  __shared__ float oas[64 * 100];

  // ---- phase 1: stage query (64 x 256 fp32 -> bf16) ----
#pragma unroll
  for (int i = 0; i < 16; ++i) {
    int g = i * 256 + t;
    int row = g >> 6, c4 = g & 63;
    float4 f = *(const float4*)(query + (size_t)(gm0 + row) * 256 + c4 * 4);
    bf16x4 hh;
    hh[0] = (__bf16)f.x; hh[1] = (__bf16)f.y;
    hh[2] = (__bf16)f.z; hh[3] = (__bf16)f.w;
    *(bf16x4*)(&As[row * LDSP + c4 * 4]) = hh;
  }
  __syncthreads();

  // ---- phase 2: oa GEMM (wave: 2 m-tiles x 3 n-tiles) ----
  {
    const int wm = (wave & 1) * 32;
    const int n0 = (wave >> 1) * 48;
    f32x4 acc[2][3];
#pragma unroll
    for (int mt = 0; mt < 2; ++mt)
#pragma unroll
      for (int nt = 0; nt < 3; ++nt) acc[mt][nt] = (f32x4){0.f, 0.f, 0.f, 0.f};
#pragma unroll
    for (int kt = 0; kt < 8; ++kt) {
      const int ko = kt * 32 + q * 8;
      bf16x8 a0 = *(const bf16x8*)(&As[(wm + r) * LDSP + ko]);
      bf16x8 a1 = *(const bf16x8*)(&As[(wm + 16 + r) * LDSP + ko]);
      bf16x8 b[3];
#pragma unroll
      for (int nt = 0; nt < 3; ++nt)
        b[nt] = *(const bf16x8*)(btoa + (size_t)(n0 + nt * 16 + r) * 256 + ko);
#pragma unroll
      for (int nt = 0; nt < 3; ++nt) {
        acc[0][nt] = __builtin_amdgcn_mfma_f32_16x16x32_bf16(a0, b[nt], acc[0][nt], 0, 0, 0);
        acc[1][nt] = __builtin_amdgcn_mfma_f32_16x16x32_bf16(a1, b[nt], acc[1][nt], 0, 0, 0);
      }
    }
#pragma unroll
    for (int mt = 0; mt < 2; ++mt)
#pragma unroll
      for (int nt = 0; nt < 3; ++nt)
#pragma unroll
        for (int rr = 0; rr < 4; ++rr) {
          int rl = wm + mt * 16 + q * 4 + rr;
          int col = n0 + nt * 16 + r;
          oas[rl * 100 + col] = acc[mt][nt][rr] + bias96[col];
        }
  }
  __syncthreads();  // oas ready; all As reads drained -> As reusable

  // ---- phase 3: sample 64 queries, write attn tile into As ----
  {
    const int qrow = t >> 2;
    const int c8 = (t & 3) * 8;
    const int row = gm0 + qrow;
    const int b = row >> 14;  // nq = 16384
    const int qi = row & (NQ - 1);
    const int x = qi & (W_IMG - 1);
    const int y = qi >> 7;
    const float* oar = &oas[qrow * 100];
#pragma unroll
    for (int h = 0; h < NH; ++h) {
      float l0 = oar[64 + h * 4 + 0];
      float l1 = oar[64 + h * 4 + 1];
      float l2 = oar[64 + h * 4 + 2];
      float l3 = oar[64 + h * 4 + 3];
      float mx = fmaxf(fmaxf(l0, l1), fmaxf(l2, l3));
      float e0 = __expf(l0 - mx), e1 = __expf(l1 - mx);
      float e2 = __expf(l2 - mx), e3 = __expf(l3 - mx);
      float inv = 1.f / (e0 + e1 + e2 + e3);
      float awp[4] = {e0 * inv, e1 * inv, e2 * inv, e3 * inv};

      // -- stage 1: all 16 byte-offsets + weights --
      int offs[16];
      float wvs[16];
#pragma unroll
      for (int p = 0; p < NP; ++p) {
        float ox = oar[h * 8 + p * 2 + 0];
        float oy = oar[h * 8 + p * 2 + 1];
        float ix = (float)x + ox;
        float iy = (float)y + oy;
        float x0f = floorf(ix), y0f = floorf(iy);
        float wx1 = ix - x0f, wy1 = iy - y0f;
        int x0 = (int)x0f, y0 = (int)y0f;
        float wgt[4] = {(1.f - wx1) * (1.f - wy1), wx1 * (1.f - wy1),
                        (1.f - wx1) * wy1, wx1 * wy1};
        int xs[4] = {x0, x0 + 1, x0, x0 + 1};
        int ysv[4] = {y0, y0, y0 + 1, y0 + 1};
#pragma unroll
        for (int c = 0; c < 4; ++c) {
          int xi = xs[c], yi = ysv[c];
          bool valid = (xi >= 0) & (xi < W_IMG) & (yi >= 0) & (yi < H_IMG);
          int xc = xi < 0 ? 0 : (xi > W_IMG - 1 ? W_IMG - 1 : xi);
          int yc = yi < 0 ? 0 : (yi > H_IMG - 1 ? H_IMG - 1 : yi);
          offs[p * 4 + c] = (yc * W_IMG + xc) * (DH * 2);  // byte offset into head plane
          wvs[p * 4 + c] = awp[p] * wgt[c] * (valid ? 1.f : 0.f);
        }
      }

      // -- stage 2: issue all 16 loads as a batch --
      const char* vb =
          (const char*)v + ((size_t)h * M + (size_t)b * NQ) * (DH * 2) + c8 * 2;
      bf16x8 g[16];
#pragma unroll
      for (int i = 0; i < 16; ++i) g[i] = *(const bf16x8*)(vb + offs[i]);

      // -- stage 3: accumulate --
      float fa[8] = {0.f, 0.f, 0.f, 0.f, 0.f, 0.f, 0.f, 0.f};
#pragma unroll
      for (int i = 0; i < 16; ++i) {
        float wv = wvs[i];
#pragma unroll
        for (int j = 0; j < 8; ++j) fa[j] += wv * (float)g[i][j];
      }

      bf16x8 o;
#pragma unroll
      for (int j = 0; j < 8; ++j) o[j] = (__bf16)fa[j];
      *(bf16x8*)(&As[qrow * LDSP + h * DH + c8]) = o;
    }
  }
  __syncthreads();  // attn tile ready in As

  // ---- phase 4: out GEMM (wave: all 64 rows x 64 cols = 4x4 tiles) ----
  {
    const int wn = wave * 64;
    f32x4 acc[4][4];
#pragma unroll
    for (int mt = 0; mt < 4; ++mt)
#pragma unroll
      for (int nt = 0; nt < 4; ++nt) acc[mt][nt] = (f32x4){0.f, 0.f, 0.f, 0.f};
#pragma unroll
    for (int kt = 0; kt < 8; ++kt) {
      const int ko = kt * 32 + q * 8;
      bf16x8 a[4], b[4];
#pragma unroll
      for (int mt = 0; mt < 4; ++mt)
        a[mt] = *(const bf16x8*)(&As[(mt * 16 + r) * LDSP + ko]);
#pragma unroll
      for (int nt = 0; nt < 4; ++nt)
        b[nt] = *(const bf16x8*)(bto + (size_t)(wn + nt * 16 + r) * 256 + ko);
#pragma unroll
      for (int mt = 0; mt < 4; ++mt)
#pragma unroll
        for (int nt = 0; nt < 4; ++nt)
          acc[mt][nt] =
              __builtin_amdgcn_mfma_f32_16x16x32_bf16(a[mt], b[nt], acc[mt][nt], 0, 0, 0);
    }
#pragma unroll
    for (int mt = 0; mt < 4; ++mt)
#pragma unroll
      for (int nt = 0; nt < 4; ++nt)
#pragma unroll
        for (int rr = 0; rr < 4; ++rr) {
          int row = gm0 + mt * 16 + q * 4 + rr;
          int col = wn + nt * 16 + r;
          out[(size_t)row * 256 + col] =
              acc[mt][nt][rr] + b_out[col] + query[(size_t)row * 256 + col];
        }
  }
}

extern "C" void kernel_launch(void* const* d_in, const int* in_sizes, int n_in,
                              void* d_out, int out_size, void* d_ws, size_t ws_size,
                              hipStream_t stream) {
  const float* query  = (const float*)d_in[0];
  const float* value  = (const float*)d_in[1];
  const float* W_off  = (const float*)d_in[2];
  const float* b_off  = (const float*)d_in[3];
  const float* W_attn = (const float*)d_in[4];
  const float* b_attn = (const float*)d_in[5];
  const float* W_val  = (const float*)d_in[6];
  const float* b_val  = (const float*)d_in[7];
  const float* W_out  = (const float*)d_in[8];
  const float* b_out  = (const float*)d_in[9];
  float* out = (float*)d_out;

  char* ws = (char*)d_ws;
  __bf16* btv    = (__bf16*)(ws + 0);          // 128 KB
  __bf16* bto    = (__bf16*)(ws + 131072);     // 128 KB
  __bf16* btoa   = (__bf16*)(ws + 262144);     // 48 KB
  float*  bias96 = (float*)(ws + 311296);      // 384 B
  __bf16* v      = (__bf16*)(ws + 524288);     // 16 MB (bf16, head-planar)

  const int M = in_sizes[0] / CIN;  // 32768 = bs * nq

  prep_weights<<<256, 256, 0, stream>>>(W_val, W_out, W_off, W_attn,
                                        b_off, b_attn, btv, bto, btoa, bias96);
  gemm_v<<<M / VQB, 256, 0, stream>>>(value, btv, b_val, v, M);
  oa_sample_out<<<M / 64, 256, 0, stream>>>(query, btoa, bias96, v, bto, b_out, out, M);
}

// Round 6
// 164.761 us; speedup vs baseline: 1.0347x; 1.0109x over previous
//
#include <hip/hip_runtime.h>

#define H_IMG 128
#define W_IMG 128
#define NQ (H_IMG * W_IMG)
#define CIN 256
#define NH 8
#define NP 4
#define DH 32
#define LDSP 264  // padded LDS row stride (16-bit elems); 264%32=8 -> 2-way max aliasing (free)

typedef __bf16 bf16x4 __attribute__((ext_vector_type(4)));
typedef __bf16 bf16x8 __attribute__((ext_vector_type(8)));
typedef _Float16 f16x8 __attribute__((ext_vector_type(8)));
typedef float f32x4 __attribute__((ext_vector_type(4)));

// ---------------- weight prep: transpose to BT[N][K]; btv/btoa bf16, bto f16 -------
__global__ __launch_bounds__(256) void prep_weights(
    const float* __restrict__ Wval, const float* __restrict__ Wout,
    const float* __restrict__ Woff, const float* __restrict__ Wattn,
    const float* __restrict__ boff, const float* __restrict__ battn,
    __bf16* __restrict__ btv, _Float16* __restrict__ bto,
    __bf16* __restrict__ btoa, float* __restrict__ bias96) {
  int id = blockIdx.x * 256 + threadIdx.x;
  if (id < 256 * 256) {
    int n = id >> 8, k = id & 255;
    btv[n * 256 + k] = (__bf16)Wval[k * 256 + n];
    bto[n * 256 + k] = (_Float16)Wout[k * 256 + n];
  }
  if (id < 96 * 256) {
    int n = id >> 8, k = id & 255;
    float w = (n < 64) ? Woff[k * 64 + n] : Wattn[k * 32 + (n - 64)];
    btoa[n * 256 + k] = (__bf16)w;
  }
  if (id < 96) {
    bias96[id] = (id < 64) ? boff[id] : battn[id - 64];
  }
}

// ---------------- K1: v = value @ W_val + b_val (head-planar f16 out) --------------
// EXACT R3 structure (64-row blocks, 512 = 2/CU). Round-5 proved v's producer block
// structure is load-bearing: the 32-row producer made K2's 256 MB of v re-reads fall
// from L2-speed to L3-speed (+45 us on K2, identical FETCH). Only change here: v is
// stored as f16 (for K2's packed-f16 sampling accumulate). DO NOT retile this kernel.
__global__ __launch_bounds__(256) void gemm_v(
    const float* __restrict__ A, const __bf16* __restrict__ BT,
    const float* __restrict__ bias, _Float16* __restrict__ v, int M) {
  const int t = threadIdx.x;
  const int lane = t & 63;
  const int wave = t >> 6;
  const int r = lane & 15;
  const int q = lane >> 4;
  const int gm0 = blockIdx.x * 64;
  const int wn = wave * 64;

  __shared__ __bf16 As[64 * LDSP];

#pragma unroll
  for (int i = 0; i < 16; ++i) {
    int g = i * 256 + t;
    int row = g >> 6, c4 = g & 63;
    float4 f = *(const float4*)(A + (size_t)(gm0 + row) * 256 + c4 * 4);
    bf16x4 hh;
    hh[0] = (__bf16)f.x; hh[1] = (__bf16)f.y;
    hh[2] = (__bf16)f.z; hh[3] = (__bf16)f.w;
    *(bf16x4*)(&As[row * LDSP + c4 * 4]) = hh;
  }
  __syncthreads();

  f32x4 acc[4][4];
#pragma unroll
  for (int mt = 0; mt < 4; ++mt)
#pragma unroll
    for (int nt = 0; nt < 4; ++nt) acc[mt][nt] = (f32x4){0.f, 0.f, 0.f, 0.f};

#pragma unroll
  for (int kt = 0; kt < 8; ++kt) {
    const int ko = kt * 32 + q * 8;
    bf16x8 a[4], b[4];
#pragma unroll
    for (int mt = 0; mt < 4; ++mt)
      a[mt] = *(const bf16x8*)(&As[(mt * 16 + r) * LDSP + ko]);
#pragma unroll
    for (int nt = 0; nt < 4; ++nt)
      b[nt] = *(const bf16x8*)(BT + (size_t)(wn + nt * 16 + r) * 256 + ko);
#pragma unroll
    for (int mt = 0; mt < 4; ++mt)
#pragma unroll
      for (int nt = 0; nt < 4; ++nt)
        acc[mt][nt] =
            __builtin_amdgcn_mfma_f32_16x16x32_bf16(a[mt], b[nt], acc[mt][nt], 0, 0, 0);
  }

  // epilogue: head-planar scatter v[head][row][col&31] (f16)
#pragma unroll
  for (int mt = 0; mt < 4; ++mt)
#pragma unroll
    for (int nt = 0; nt < 4; ++nt)
#pragma unroll
      for (int rr = 0; rr < 4; ++rr) {
        int row = gm0 + mt * 16 + q * 4 + rr;
        int col = wn + nt * 16 + r;
        v[((size_t)(col >> 5) * M + row) * 32 + (col & 31)] =
            (_Float16)(acc[mt][nt][rr] + bias[col]);
      }
}

// ---------------- K2: oa GEMM + sampling + output GEMM, fully fused ----------------
// R3 structure (best measured: ~46 us K2). 64 queries, 256 threads, 2 blocks/CU.
// Round-4 falsified occupancy scaling for this kernel; round-5 showed v-producer
// placement dominates phase-3 read speed. This round's single change: phase 3
// accumulates in packed f16 (v_pk_fma_f16 via f16x8 vector math, 4 instr per
// corner-chunk instead of 8 cvt + 8 fma), and phase 4 runs f16 MFMA on the f16
// attn tile + f16 bto. f16 has more mantissa than bf16 -> numerics improve.
__global__ __launch_bounds__(256, 2) void oa_sample_out(
    const float* __restrict__ query, const __bf16* __restrict__ btoa,
    const float* __restrict__ bias96, const _Float16* __restrict__ v,
    const _Float16* __restrict__ bto, const float* __restrict__ b_out,
    float* __restrict__ out, int M) {
  const int t = threadIdx.x;
  const int lane = t & 63;
  const int wave = t >> 6;
  const int r = lane & 15;
  const int q = lane >> 4;
  const int gm0 = blockIdx.x * 64;

  __shared__ __bf16 As[64 * LDSP];
  __shared__ float oas[64 * 100];
  _Float16* Asf = (_Float16*)As;  // phase 3/4 reuse As as f16 attn tile

  // ---- phase 1: stage query (64 x 256 fp32 -> bf16) ----
#pragma unroll
  for (int i = 0; i < 16; ++i) {
    int g = i * 256 + t;
    int row = g >> 6, c4 = g & 63;
    float4 f = *(const float4*)(query + (size_t)(gm0 + row) * 256 + c4 * 4);
    bf16x4 hh;
    hh[0] = (__bf16)f.x; hh[1] = (__bf16)f.y;
    hh[2] = (__bf16)f.z; hh[3] = (__bf16)f.w;
    *(bf16x4*)(&As[row * LDSP + c4 * 4]) = hh;
  }
  __syncthreads();

  // ---- phase 2: oa GEMM (wave: 2 m-tiles x 3 n-tiles) ----
  {
    const int wm = (wave & 1) * 32;
    const int n0 = (wave >> 1) * 48;
    f32x4 acc[2][3];
#pragma unroll
    for (int mt = 0; mt < 2; ++mt)
#pragma unroll
      for (int nt = 0; nt < 3; ++nt) acc[mt][nt] = (f32x4){0.f, 0.f, 0.f, 0.f};
#pragma unroll
    for (int kt = 0; kt < 8; ++kt) {
      const int ko = kt * 32 + q * 8;
      bf16x8 a0 = *(const bf16x8*)(&As[(wm + r) * LDSP + ko]);
      bf16x8 a1 = *(const bf16x8*)(&As[(wm + 16 + r) * LDSP + ko]);
      bf16x8 b[3];
#pragma unroll
      for (int nt = 0; nt < 3; ++nt)
        b[nt] = *(const bf16x8*)(btoa + (size_t)(n0 + nt * 16 + r) * 256 + ko);
#pragma unroll
      for (int nt = 0; nt < 3; ++nt) {
        acc[0][nt] = __builtin_amdgcn_mfma_f32_16x16x32_bf16(a0, b[nt], acc[0][nt], 0, 0, 0);
        acc[1][nt] = __builtin_amdgcn_mfma_f32_16x16x32_bf16(a1, b[nt], acc[1][nt], 0, 0, 0);
      }
    }
#pragma unroll
    for (int mt = 0; mt < 2; ++mt)
#pragma unroll
      for (int nt = 0; nt < 3; ++nt)
#pragma unroll
        for (int rr = 0; rr < 4; ++rr) {
          int rl = wm + mt * 16 + q * 4 + rr;
          int col = n0 + nt * 16 + r;
          oas[rl * 100 + col] = acc[mt][nt][rr] + bias96[col];
        }
  }
  __syncthreads();  // oas ready; all As reads drained -> As reusable

  // ---- phase 3: sample 64 queries, write f16 attn tile into As ----
  {
    const int qrow = t >> 2;
    const int c8 = (t & 3) * 8;
    const int row = gm0 + qrow;
    const int b = row >> 14;  // nq = 16384
    const int qi = row & (NQ - 1);
    const int x = qi & (W_IMG - 1);
    const int y = qi >> 7;
    const float* oar = &oas[qrow * 100];
#pragma unroll
    for (int h = 0; h < NH; ++h) {
      float l0 = oar[64 + h * 4 + 0];
      float l1 = oar[64 + h * 4 + 1];
      float l2 = oar[64 + h * 4 + 2];
      float l3 = oar[64 + h * 4 + 3];
      float mx = fmaxf(fmaxf(l0, l1), fmaxf(l2, l3));
      float e0 = __expf(l0 - mx), e1 = __expf(l1 - mx);
      float e2 = __expf(l2 - mx), e3 = __expf(l3 - mx);
      float inv = 1.f / (e0 + e1 + e2 + e3);
      float awp[4] = {e0 * inv, e1 * inv, e2 * inv, e3 * inv};

      // -- stage 1: all 16 byte-offsets + weights --
      int offs[16];
      float wvs[16];
#pragma unroll
      for (int p = 0; p < NP; ++p) {
        float ox = oar[h * 8 + p * 2 + 0];
        float oy = oar[h * 8 + p * 2 + 1];
        float ix = (float)x + ox;
        float iy = (float)y + oy;
        float x0f = floorf(ix), y0f = floorf(iy);
        float wx1 = ix - x0f, wy1 = iy - y0f;
        int x0 = (int)x0f, y0 = (int)y0f;
        float wgt[4] = {(1.f - wx1) * (1.f - wy1), wx1 * (1.f - wy1),
                        (1.f - wx1) * wy1, wx1 * wy1};
        int xs[4] = {x0, x0 + 1, x0, x0 + 1};
        int ysv[4] = {y0, y0, y0 + 1, y0 + 1};
#pragma unroll
        for (int c = 0; c < 4; ++c) {
          int xi = xs[c], yi = ysv[c];
          bool valid = (xi >= 0) & (xi < W_IMG) & (yi >= 0) & (yi < H_IMG);
          int xc = xi < 0 ? 0 : (xi > W_IMG - 1 ? W_IMG - 1 : xi);
          int yc = yi < 0 ? 0 : (yi > H_IMG - 1 ? H_IMG - 1 : yi);
          offs[p * 4 + c] = (yc * W_IMG + xc) * (DH * 2);  // byte offset into head plane
          wvs[p * 4 + c] = awp[p] * wgt[c] * (valid ? 1.f : 0.f);
        }
      }

      // -- stage 2: issue all 16 loads as a batch --
      const char* vb =
          (const char*)v + ((size_t)h * M + (size_t)b * NQ) * (DH * 2) + c8 * 2;
      f16x8 g[16];
#pragma unroll
      for (int i = 0; i < 16; ++i) g[i] = *(const f16x8*)(vb + offs[i]);

      // -- stage 3: accumulate in packed f16 (v_pk_fma_f16: 4 instr / corner) --
      f16x8 fa = {};
#pragma unroll
      for (int i = 0; i < 16; ++i) fa += g[i] * (_Float16)wvs[i];

      *(f16x8*)(&Asf[qrow * LDSP + h * DH + c8]) = fa;
    }
  }
  __syncthreads();  // f16 attn tile ready in As

  // ---- phase 4: out GEMM f16 (wave: all 64 rows x 64 cols = 4x4 tiles) ----
  {
    const int wn = wave * 64;
    f32x4 acc[4][4];
#pragma unroll
    for (int mt = 0; mt < 4; ++mt)
#pragma unroll
      for (int nt = 0; nt < 4; ++nt) acc[mt][nt] = (f32x4){0.f, 0.f, 0.f, 0.f};
#pragma unroll
    for (int kt = 0; kt < 8; ++kt) {
      const int ko = kt * 32 + q * 8;
      f16x8 a[4], b[4];
#pragma unroll
      for (int mt = 0; mt < 4; ++mt)
        a[mt] = *(const f16x8*)(&Asf[(mt * 16 + r) * LDSP + ko]);
#pragma unroll
      for (int nt = 0; nt < 4; ++nt)
        b[nt] = *(const f16x8*)(bto + (size_t)(wn + nt * 16 + r) * 256 + ko);
#pragma unroll
      for (int mt = 0; mt < 4; ++mt)
#pragma unroll
        for (int nt = 0; nt < 4; ++nt)
          acc[mt][nt] =
              __builtin_amdgcn_mfma_f32_16x16x32_f16(a[mt], b[nt], acc[mt][nt], 0, 0, 0);
    }
#pragma unroll
    for (int mt = 0; mt < 4; ++mt)
#pragma unroll
      for (int nt = 0; nt < 4; ++nt)
#pragma unroll
        for (int rr = 0; rr < 4; ++rr) {
          int row = gm0 + mt * 16 + q * 4 + rr;
          int col = wn + nt * 16 + r;
          out[(size_t)row * 256 + col] =
              acc[mt][nt][rr] + b_out[col] + query[(size_t)row * 256 + col];
        }
  }
}

extern "C" void kernel_launch(void* const* d_in, const int* in_sizes, int n_in,
                              void* d_out, int out_size, void* d_ws, size_t ws_size,
                              hipStream_t stream) {
  const float* query  = (const float*)d_in[0];
  const float* value  = (const float*)d_in[1];
  const float* W_off  = (const float*)d_in[2];
  const float* b_off  = (const float*)d_in[3];
  const float* W_attn = (const float*)d_in[4];
  const float* b_attn = (const float*)d_in[5];
  const float* W_val  = (const float*)d_in[6];
  const float* b_val  = (const float*)d_in[7];
  const float* W_out  = (const float*)d_in[8];
  const float* b_out  = (const float*)d_in[9];
  float* out = (float*)d_out;

  char* ws = (char*)d_ws;
  __bf16*   btv    = (__bf16*)(ws + 0);          // 128 KB
  _Float16* bto    = (_Float16*)(ws + 131072);   // 128 KB
  __bf16*   btoa   = (__bf16*)(ws + 262144);     // 48 KB
  float*    bias96 = (float*)(ws + 311296);      // 384 B
  _Float16* v      = (_Float16*)(ws + 524288);   // 16 MB (f16, head-planar)

  const int M = in_sizes[0] / CIN;  // 32768 = bs * nq

  prep_weights<<<256, 256, 0, stream>>>(W_val, W_out, W_off, W_attn,
                                        b_off, b_attn, btv, bto, btoa, bias96);
  gemm_v<<<M / 64, 256, 0, stream>>>(value, btv, b_val, v, M);
  oa_sample_out<<<M / 64, 256, 0, stream>>>(query, btoa, bias96, v, bto, b_out, out, M);
}